// Round 12
// baseline (422.520 us; speedup 1.0000x reference)
//
#include <hip/hip_runtime.h>

typedef short bf16x8 __attribute__((ext_vector_type(8)));
typedef float f32x4 __attribute__((ext_vector_type(4)));
typedef unsigned short u16;
typedef unsigned int u32;

#define NN 100000
#define NE 600000
#define PART 12500        // NN / 8
#define ECH 4688          // ceil(NE / 128)
#define SL (NN * 16)      // u16 elements per feature slice

__device__ __forceinline__ u16 f2b(float f) {
    u32 u = __float_as_uint(f);
    return (u16)((u + 0x7FFFu + ((u >> 16) & 1u)) >> 16);
}

// ---------------- fused setup: x->bf16 slice-major | weight transpose+bf16 ----------------
// x16s layout: [slice 0..7][node][16 feats] (slice s = feats 16s..16s+15)
__global__ void fused_setup(
    const float* __restrict__ x, u16* __restrict__ xo,
    const float* __restrict__ Ws0_0, const float* __restrict__ Ws0_1,
    const float* __restrict__ Wn0_0, const float* __restrict__ Wn0_1,
    const float* __restrict__ Wp_0,  const float* __restrict__ Wp_1,
    const float* __restrict__ Ws1_0, const float* __restrict__ Ws1_1,
    const float* __restrict__ Wn1_0, const float* __restrict__ Wn1_1,
    const float* __restrict__ b0_0, const float* __restrict__ b0_1,
    const float* __restrict__ b1_0, const float* __restrict__ b1_1,
    const float* __restrict__ bp_0, const float* __restrict__ bp_1,
    u16* __restrict__ w, float* __restrict__ bsum0, float* __restrict__ bsum1,
    float* __restrict__ bpc)
{
    int bb = blockIdx.x;
    if (bb < 12500) {                         // x -> bf16 slice-major
        int t = bb * 256 + threadIdx.x;
        const float4 v = reinterpret_cast<const float4*>(x)[t];
        ushort4 r; r.x = f2b(v.x); r.y = f2b(v.y); r.z = f2b(v.z); r.w = f2b(v.w);
        int node = t >> 5;
        int fq = (t & 31) << 2;               // 0,4,...,124
        *reinterpret_cast<ushort4*>(xo + (size_t)(fq >> 4) * SL + node * 16 + (fq & 15)) = r;
    } else {                                  // weight prep
        int t = (bb - 12500) * 256 + threadIdx.x;
        if (t < 81920) {                      // five 128x128 transposes
            int m = t >> 14, u = t & 16383;
            int n = u >> 7, k = u & 127;
            float v;
            if (m == 0)      v = Ws0_0[k * 128 + n] + Ws0_1[k * 128 + n];
            else if (m == 1) v = Wn0_0[k * 128 + n];
            else if (m == 2) v = Wn0_1[k * 128 + n];
            else if (m == 3) v = Wp_0[k * 128 + n];
            else             v = Wp_1[k * 128 + n];
            w[t] = f2b(v);
        } else if (t < 106496) {              // three 64x128 transposed
            int u = t - 81920;
            int m = u >> 13; u &= 8191;
            int n = u >> 7, k = u & 127;
            float v;
            if (m == 0)      v = Ws1_0[k * 64 + n] + Ws1_1[k * 64 + n];
            else if (m == 1) v = Wn1_0[k * 64 + n];
            else             v = Wn1_1[k * 64 + n];
            w[t] = f2b(v);
        } else if (t < 106624) {
            int i = t - 106496; bsum0[i] = b0_0[i] + b0_1[i];
        } else if (t < 106688) {
            int i = t - 106624; bsum1[i] = b1_0[i] + b1_1[i];
        } else if (t < 106944) {
            int i = t - 106688; bpc[i] = (i < 128) ? bp_0[i] : bp_1[i - 128];
        }
    }
}

// ---------------- XCD-partitioned degree count, co-resident grid (2048 blocks) ----------------
__global__ __launch_bounds__(256) void deg_part(
    const int* __restrict__ d0, const int* __restrict__ d1,
    int* __restrict__ g0, int* __restrict__ g1)
{
    int part = blockIdx.x & 7;
    int sub = blockIdx.x >> 3;
    int rel = sub & 1;
    int chunk = sub >> 1;
    const int lo = part * PART, hi = lo + PART;
    const int* d = rel ? d1 : d0;
    int* g = rel ? g1 : g0;
    const int e0 = chunk * ECH;
    const int e1 = min(e0 + ECH, NE);
    for (int e = e0 + threadIdx.x; e < e1; e += 256) {
        int dd = d[e];
        if (dd >= lo && dd < hi) atomicAdd(&g[dd], 1);
    }
}

// ---------------- prefix scan ----------------
__global__ void scan_local(const int* __restrict__ deg0, const int* __restrict__ deg1,
                           int* __restrict__ offs0, int* __restrict__ offs1,
                           int* __restrict__ bsA, int* __restrict__ bsB)
{
    __shared__ int sm[1024];
    int rel = blockIdx.x >= 98;
    int blk = blockIdx.x - rel * 98;
    const int* in = rel ? deg1 : deg0;
    int* out = rel ? offs1 : offs0;
    int* bsum = rel ? bsB : bsA;
    int t = threadIdx.x;
    int i = blk * 1024 + t;
    int v = (i < NN) ? in[i] : 0;
    sm[t] = v;
    __syncthreads();
    for (int off = 1; off < 1024; off <<= 1) {
        int add = (t >= off) ? sm[t - off] : 0;
        __syncthreads();
        sm[t] += add;
        __syncthreads();
    }
    if (i < NN) out[i] = sm[t] - v;            // exclusive
    if (t == 1023) bsum[blk] = sm[1023];
}

__global__ void scan_bsums(int* __restrict__ bsA, int* __restrict__ bsB)
{
    __shared__ int sm[128];
    int* bsum = blockIdx.x ? bsB : bsA;
    int t = threadIdx.x;
    int v = (t < 98) ? bsum[t] : 0;
    sm[t] = v;
    __syncthreads();
    for (int off = 1; off < 128; off <<= 1) {
        int add = (t >= off) ? sm[t - off] : 0;
        __syncthreads();
        sm[t] += add;
        __syncthreads();
    }
    if (t < 98) bsum[t] = sm[t] - v;           // exclusive
}

__global__ void scan_add(int* __restrict__ offs0, int* __restrict__ offs1,
                         const int* __restrict__ bsA, const int* __restrict__ bsB,
                         int* __restrict__ cur0, int* __restrict__ cur1)
{
    int rel = blockIdx.x >= 392;
    int i = (blockIdx.x - rel * 392) * 256 + threadIdx.x;
    int* offs = rel ? offs1 : offs0;
    int* cur = rel ? cur1 : cur0;
    const int* bsum = rel ? bsB : bsA;
    if (i < NN) {
        int v = offs[i] + bsum[i >> 10];
        offs[i] = v;
        cur[i] = v;
    }
    if (i == 0) offs[NN] = NE;
}

// ---------------- CSR build, XCD-partitioned, co-resident grid (2048 blocks) ----------------
// Entry = (src << 15) | (top 15 bits of f32(ew), round-to-nearest); decode = as_float(E<<17).
__global__ __launch_bounds__(256) void build_csr_part(
    const int* __restrict__ src0, const int* __restrict__ dst0,
    const float* __restrict__ ew0,
    const int* __restrict__ src1, const int* __restrict__ dst1,
    const float* __restrict__ ew1,
    int* __restrict__ cur0, int* __restrict__ cur1,
    u32* __restrict__ csr0, u32* __restrict__ csr1)
{
    int part = blockIdx.x & 7;
    int sub = blockIdx.x >> 3;
    int rel = sub & 1;
    int chunk = sub >> 1;
    const int lo = part * PART, hi = lo + PART;
    const int* src = rel ? src1 : src0;
    const int* dst = rel ? dst1 : dst0;
    const float* ew = rel ? ew1 : ew0;
    int* cur = rel ? cur1 : cur0;
    u32* csr = rel ? csr1 : csr0;
    const int e0 = chunk * ECH;
    const int e1 = min(e0 + ECH, NE);
    for (int e = e0 + threadIdx.x; e < e1; e += 256) {
        int d = dst[e];
        if (d >= lo && d < hi) {
            int p = atomicAdd(&cur[d], 1);
            u32 q = (__float_as_uint(ew[e]) + 0x10000u) >> 17;
            csr[p] = ((u32)src[e] << 15) | q;
        }
    }
}

// ---------------- slice-partitioned gather: slice s handled on XCD s ----------------
// F/out slice-major [8][NN][16]. 2048 co-resident blocks; part = bid&7 -> slice AND XCD.
// Per wave: 8 groups x 8 lanes; group walks one node's edges, 8-deep batched loads.
// REL2: two relations in one dispatch (same table; mean). Else: one relation (max).
template<bool MAXAGG, bool REL2>
__global__ __launch_bounds__(256) void gather_slice(
    const u16* __restrict__ Fs,
    const int* __restrict__ offs0, const u32* __restrict__ csr0, u16* __restrict__ o0,
    const int* __restrict__ offs1, const u32* __restrict__ csr1, u16* __restrict__ o1)
{
    const int part = blockIdx.x & 7;
    int sub = blockIdx.x >> 3;
    const int* offs = offs0;
    const u32* csr = csr0;
    u16* outs = o0;
    int nper;
    if (REL2) {
        int rel = sub & 1; sub >>= 1;         // sub 0..127
        if (rel) { offs = offs1; csr = csr1; outs = o1; }
        nper = 782;
    } else {
        nper = 391;                           // sub 0..255
    }
    const int l = threadIdx.x & 63;
    const int wv = threadIdx.x >> 6;
    const int g = l >> 3, lf = l & 7;
    const u16* F = Fs + (size_t)part * SL + (lf << 1);
    u16* out = outs + (size_t)part * SL + (lf << 1);

    const int nbeg = sub * nper;
    const int nend = min(nbeg + nper, NN);
    for (int nb = nbeg + (wv << 3); nb < nend; nb += 32) {
        int node = nb + g;
        int nc = min(node, NN - 1);
        int beg = offs[nc];
        int cnt = (node < nend) ? (offs[nc + 1] - beg) : 0;
        int last = max(cnt - 1, 0);
        float a0 = 0.f, a1 = 0.f;
        for (int base = 0; __any(base < cnt); base += 8) {
            u32 E[8];
#pragma unroll
            for (int j = 0; j < 8; ++j)
                E[j] = csr[beg + min(base + j, last)];
            u32 v[8];
#pragma unroll
            for (int j = 0; j < 8; ++j)
                v[j] = *reinterpret_cast<const u32*>(F + ((size_t)(E[j] >> 15) << 4));
#pragma unroll
            for (int j = 0; j < 8; ++j) {
                float wgt = (base + j < cnt) ? __uint_as_float(E[j] << 17) : 0.f;
                float f0 = __uint_as_float(v[j] << 16);
                float f1 = __uint_as_float(v[j] & 0xFFFF0000u);
                if (MAXAGG) {
                    a0 = fmaxf(a0, f0 * wgt);
                    a1 = fmaxf(a1, f1 * wgt);
                } else {
                    a0 = fmaf(f0, wgt, a0);
                    a1 = fmaf(f1, wgt, a1);
                }
            }
        }
        if (node < nend) {
            float s = MAXAGG ? 1.f : 1.f / fmaxf((float)cnt, 1.f);
            ushort2 r; r.x = f2b(a0 * s); r.y = f2b(a1 * s);
            *reinterpret_cast<ushort2*>(out + (size_t)node * 16) = r;
        }
    }
}

// ---------------- register-B multi-pair MFMA GEMM (no LDS, no barriers) ----------------
// SLICEMASK bit p: A_p is slice-major [8][NN][16]. SLICEC: bf16 C written slice-major.
template<int NPAIR, int COLGROUPS, int WAVES, bool RELU, bool OUTF32, bool DUAL,
         int SLICEMASK, bool SLICEC>
__global__ __launch_bounds__(WAVES * 64, 2) void gemm_reg(
    const u16* __restrict__ A0, const u16* __restrict__ A1, const u16* __restrict__ A2,
    const u16* __restrict__ BT, const float* __restrict__ bias,
    float* __restrict__ outF, u16* __restrict__ outB, u16* __restrict__ outB2)
{
    constexpr int NC = COLGROUPS * 32;
    constexpr int RT = WAVES / COLGROUPS;
    constexpr int OST = DUAL ? (NC / 2) : NC;
    constexpr int NTILES = NN / 32;
    const int w = threadIdx.x >> 6, l = threadIdx.x & 63;
    const int cg = w % COLGROUPS, rsub = w / COLGROUPS;
    const int l15 = l & 15, lk = (l >> 4) << 3, rq = (l >> 4) << 2;

    bf16x8 bfr[NPAIR][4][2];
#pragma unroll
    for (int p = 0; p < NPAIR; ++p)
#pragma unroll
        for (int ks = 0; ks < 4; ++ks)
#pragma unroll
            for (int cf = 0; cf < 2; ++cf) {
                int n = p * NC + cg * 32 + cf * 16 + l15;
                bfr[p][ks][cf] = *reinterpret_cast<const bf16x8*>(BT + (size_t)n * 128 + ks * 32 + lk);
            }

    const u16* As[3] = {A0, A1, A2};
    const float bv0 = bias[cg * 32 + l15];
    const float bv1 = bias[cg * 32 + 16 + l15];

    for (int tile = blockIdx.x * RT + rsub; tile < NTILES; tile += gridDim.x * RT) {
        const size_t rowbase = (size_t)tile * 32;

        // ---- phase 1: issue ALL A loads ----
        bf16x8 af[NPAIR][4][2];
#pragma unroll
        for (int p = 0; p < NPAIR; ++p) {
            const u16* A = As[p];
            const bool sl = (SLICEMASK >> p) & 1;
#pragma unroll
            for (int ks = 0; ks < 4; ++ks) {
                const int k0 = ks * 32 + lk;
                size_t off0, off1;
                if (sl) {
                    off0 = (size_t)(k0 >> 4) * SL + (rowbase + l15) * 16 + (k0 & 15);
                    off1 = (size_t)(k0 >> 4) * SL + (rowbase + 16 + l15) * 16 + (k0 & 15);
                } else {
                    off0 = (rowbase + l15) * (size_t)128 + k0;
                    off1 = (rowbase + 16 + l15) * (size_t)128 + k0;
                }
                af[p][ks][0] = *reinterpret_cast<const bf16x8*>(A + off0);
                af[p][ks][1] = *reinterpret_cast<const bf16x8*>(A + off1);
            }
        }

        // ---- phase 2: all MFMAs ----
        f32x4 acc[2][2];
#pragma unroll
        for (int rf = 0; rf < 2; ++rf)
#pragma unroll
            for (int cf = 0; cf < 2; ++cf)
                acc[rf][cf] = f32x4{0.f, 0.f, 0.f, 0.f};

#pragma unroll
        for (int p = 0; p < NPAIR; ++p)
#pragma unroll
            for (int ks = 0; ks < 4; ++ks) {
                acc[0][0] = __builtin_amdgcn_mfma_f32_16x16x32_bf16(af[p][ks][0], bfr[p][ks][0], acc[0][0], 0, 0, 0);
                acc[0][1] = __builtin_amdgcn_mfma_f32_16x16x32_bf16(af[p][ks][0], bfr[p][ks][1], acc[0][1], 0, 0, 0);
                acc[1][0] = __builtin_amdgcn_mfma_f32_16x16x32_bf16(af[p][ks][1], bfr[p][ks][0], acc[1][0], 0, 0, 0);
                acc[1][1] = __builtin_amdgcn_mfma_f32_16x16x32_bf16(af[p][ks][1], bfr[p][ks][1], acc[1][1], 0, 0, 0);
            }

        u16* ob = outB;
        if (DUAL && cg >= 4) ob = outB2;
        const int colbase = (DUAL ? (cg & 3) : cg) * 32;
#pragma unroll
        for (int cf = 0; cf < 2; ++cf) {
            const int col = colbase + cf * 16 + l15;
            const float bv = cf ? bv1 : bv0;
            const size_t sbase = (size_t)((colbase + cf * 16) >> 4) * SL;
#pragma unroll
            for (int rf = 0; rf < 2; ++rf) {
#pragma unroll
                for (int j = 0; j < 4; ++j) {
                    const size_t row = rowbase + rf * 16 + rq + j;
                    float v = acc[rf][cf][j] + bv;
                    if (RELU) v = fmaxf(v, 0.f);
                    if (OUTF32)      outF[row * OST + col] = v;
                    else if (SLICEC) ob[sbase + row * 16 + l15] = f2b(v);
                    else             ob[row * OST + col] = f2b(v);
                }
            }
        }
    }
}

extern "C" void kernel_launch(void* const* d_in, const int* in_sizes, int n_in,
                              void* d_out, int out_size, void* d_ws, size_t ws_size,
                              hipStream_t stream)
{
    const float* x     = (const float*)d_in[0];
    const int*   src0  = (const int*)d_in[1];
    const int*   dst0  = (const int*)d_in[2];
    const float* ew0   = (const float*)d_in[3];
    const int*   src1  = (const int*)d_in[4];
    const int*   dst1  = (const int*)d_in[5];
    const float* ew1   = (const float*)d_in[6];
    const float* Ws0_0 = (const float*)d_in[7];
    const float* Wn0_0 = (const float*)d_in[8];
    const float* b0_0  = (const float*)d_in[9];
    const float* Wp_0  = (const float*)d_in[10];
    const float* bp_0  = (const float*)d_in[11];
    const float* Ws1_0 = (const float*)d_in[12];
    const float* Wn1_0 = (const float*)d_in[13];
    const float* b1_0  = (const float*)d_in[14];
    const float* Ws0_1 = (const float*)d_in[15];
    const float* Wn0_1 = (const float*)d_in[16];
    const float* b0_1  = (const float*)d_in[17];
    const float* Wp_1  = (const float*)d_in[18];
    const float* bp_1  = (const float*)d_in[19];
    const float* Ws1_1 = (const float*)d_in[20];
    const float* Wn1_1 = (const float*)d_in[21];
    const float* b1_1  = (const float*)d_in[22];

    char* ws = (char*)d_ws;
    u16*   x16s  = (u16*)(ws + 0);            // x bf16 slice-major; reused as hp0s
    u16*   h16   = (u16*)(ws + 25600000);     // row-major
    u16*   a0s   = (u16*)(ws + 51200000);     // agg r0 slice-major
    u16*   a1s   = (u16*)(ws + 76800000);     // agg r1 slice-major
    u16*   hp1s  = (u16*)(ws + 102400000);    // hp r1 slice-major
    u32*   csr0  = (u32*)(ws + 128000000);
    u32*   csr1  = (u32*)(ws + 130400032);
    int*   offs0 = (int*)(ws + 132800064);
    int*   offs1 = (int*)(ws + 133200080);
    int*   cur0  = (int*)(ws + 133600096);
    int*   cur1  = (int*)(ws + 134000096);
    int*   deg0  = (int*)(ws + 134400096);
    int*   deg1  = (int*)(ws + 134800096);
    int*   bsA   = (int*)(ws + 135200096);
    int*   bsB   = (int*)(ws + 135200608);
    u16*   wts   = (u16*)(ws + 135201120);
    float* bsum0 = (float*)(ws + 135414112);
    float* bsum1 = (float*)(ws + 135414624);
    float* bpc   = (float*)(ws + 135415136);

    u16* hp0s = x16s;                         // x16s dead after layer-0 GEMM

    hipMemsetAsync(deg0, 0, 800000, stream);
    deg_part<<<2048, 256, 0, stream>>>(dst0, dst1, deg0, deg1);
    fused_setup<<<12918, 256, 0, stream>>>(
        x, x16s, Ws0_0, Ws0_1, Wn0_0, Wn0_1, Wp_0, Wp_1,
        Ws1_0, Ws1_1, Wn1_0, Wn1_1, b0_0, b0_1, b1_0, b1_1, bp_0, bp_1,
        wts, bsum0, bsum1, bpc);

    scan_local<<<196, 1024, 0, stream>>>(deg0, deg1, offs0, offs1, bsA, bsB);
    scan_bsums<<<2, 128, 0, stream>>>(bsA, bsB);
    scan_add<<<784, 256, 0, stream>>>(offs0, offs1, bsA, bsB, cur0, cur1);
    build_csr_part<<<2048, 256, 0, stream>>>(
        src0, dst0, ew0, src1, dst1, ew1, cur0, cur1, csr0, csr1);

    // ---- layer 0: mean gather (both relations, x16s L2-resident per XCD) ----
    gather_slice<false, true><<<2048, 256, 0, stream>>>(
        x16s, offs0, csr0, a0s, offs1, csr1, a1s);
    gemm_reg<3, 4, 4, true, false, false, 0b111, false><<<1024, 256, 0, stream>>>(
        x16s, a0s, a1s, wts, bsum0, nullptr, h16, nullptr);

    // ---- layer 1: dual Wp GEMM -> slice-major hp; max gathers per relation ----
    gemm_reg<1, 8, 8, true, false, true, 0, true><<<512, 512, 0, stream>>>(
        h16, nullptr, nullptr, wts + 49152, bpc, nullptr, hp0s, hp1s);
    gather_slice<true, false><<<2048, 256, 0, stream>>>(
        hp0s, offs0, csr0, a0s, nullptr, nullptr, nullptr);
    gather_slice<true, false><<<2048, 256, 0, stream>>>(
        hp1s, offs1, csr1, a1s, nullptr, nullptr, nullptr);
    gemm_reg<3, 2, 4, false, true, false, 0b110, false><<<782, 256, 0, stream>>>(
        h16, a0s, a1s, wts + 81920, bsum1, (float*)d_out, nullptr, nullptr);
}

// Round 13
// 405.516 us; speedup vs baseline: 1.0419x; 1.0419x over previous
//
#include <hip/hip_runtime.h>

typedef short bf16x8 __attribute__((ext_vector_type(8)));
typedef float f32x4 __attribute__((ext_vector_type(4)));
typedef unsigned short u16;
typedef unsigned int u32;

#define NN 100000
#define NE 600000
#define PART 12500        // NN / 8
#define ECH 4688          // ceil(NE / 128)
#define S 4096            // gather node stride (8192 waves / 2 relations)
#define NSTEP 25          // ceil(NN / S)

__device__ __forceinline__ u16 f2b(float f) {
    u32 u = __float_as_uint(f);
    return (u16)((u + 0x7FFFu + ((u >> 16) & 1u)) >> 16);
}

// ---------------- fused setup: XCD-part deg count | x->bf16 | weight prep ----------------
// Blocks 0..2047: degree count (co-resident-first -> blockIdx&7 == XCD holds).
// Blocks 2048..14965: x conversion + weight transpose.
// wts layout (u16): 0 Wsum0T[128][128], 16384 Wn0r0T, 32768 Wn0r1T,
//   49152 Wp0T[128][128], 65536 Wp1T, 81920 Wsum1T[64][128], 90112 Wn1r0T, 98304 Wn1r1T
__global__ void fused_setup(
    const float* __restrict__ x, u16* __restrict__ xo,
    const float* __restrict__ Ws0_0, const float* __restrict__ Ws0_1,
    const float* __restrict__ Wn0_0, const float* __restrict__ Wn0_1,
    const float* __restrict__ Wp_0,  const float* __restrict__ Wp_1,
    const float* __restrict__ Ws1_0, const float* __restrict__ Ws1_1,
    const float* __restrict__ Wn1_0, const float* __restrict__ Wn1_1,
    const float* __restrict__ b0_0, const float* __restrict__ b0_1,
    const float* __restrict__ b1_0, const float* __restrict__ b1_1,
    const float* __restrict__ bp_0, const float* __restrict__ bp_1,
    u16* __restrict__ w, float* __restrict__ bsum0, float* __restrict__ bsum1,
    float* __restrict__ bpc,
    const int* __restrict__ d0, const int* __restrict__ d1,
    int* __restrict__ g0, int* __restrict__ g1)
{
    int bb = blockIdx.x;
    if (bb < 2048) {                          // XCD-partitioned degree count
        int part = bb & 7;
        int sub = bb >> 3;
        int rel = sub & 1;
        int chunk = sub >> 1;
        const int lo = part * PART, hi = lo + PART;
        const int* d = rel ? d1 : d0;
        int* g = rel ? g1 : g0;
        const int e0 = chunk * ECH;
        const int e1 = min(e0 + ECH, NE);
        for (int e = e0 + threadIdx.x; e < e1; e += 256) {
            int dd = d[e];
            if (dd >= lo && dd < hi) atomicAdd(&g[dd], 1);
        }
    } else if (bb < 14548) {                  // x -> bf16 (12500 blocks)
        int t = (bb - 2048) * 256 + threadIdx.x;
        const float4 v = reinterpret_cast<const float4*>(x)[t];
        ushort4 r; r.x = f2b(v.x); r.y = f2b(v.y); r.z = f2b(v.z); r.w = f2b(v.w);
        reinterpret_cast<ushort4*>(xo)[t] = r;
    } else {                                  // weight prep (418 blocks)
        int t = (bb - 14548) * 256 + threadIdx.x;
        if (t < 81920) {                      // five 128x128 transposes
            int m = t >> 14, u = t & 16383;
            int n = u >> 7, k = u & 127;
            float v;
            if (m == 0)      v = Ws0_0[k * 128 + n] + Ws0_1[k * 128 + n];
            else if (m == 1) v = Wn0_0[k * 128 + n];
            else if (m == 2) v = Wn0_1[k * 128 + n];
            else if (m == 3) v = Wp_0[k * 128 + n];
            else             v = Wp_1[k * 128 + n];
            w[t] = f2b(v);
        } else if (t < 106496) {              // three 64x128 transposed
            int u = t - 81920;
            int m = u >> 13; u &= 8191;
            int n = u >> 7, k = u & 127;
            float v;
            if (m == 0)      v = Ws1_0[k * 64 + n] + Ws1_1[k * 64 + n];
            else if (m == 1) v = Wn1_0[k * 64 + n];
            else             v = Wn1_1[k * 64 + n];
            w[t] = f2b(v);
        } else if (t < 106624) {
            int i = t - 106496; bsum0[i] = b0_0[i] + b0_1[i];
        } else if (t < 106688) {
            int i = t - 106624; bsum1[i] = b1_0[i] + b1_1[i];
        } else if (t < 106944) {
            int i = t - 106688; bpc[i] = (i < 128) ? bp_0[i] : bp_1[i - 128];
        }
    }
}

// ---------------- prefix scan ----------------
__global__ void scan_local(const int* __restrict__ deg0, const int* __restrict__ deg1,
                           int* __restrict__ offs0, int* __restrict__ offs1,
                           int* __restrict__ bsA, int* __restrict__ bsB)
{
    __shared__ int sm[1024];
    int rel = blockIdx.x >= 98;
    int blk = blockIdx.x - rel * 98;
    const int* in = rel ? deg1 : deg0;
    int* out = rel ? offs1 : offs0;
    int* bsum = rel ? bsB : bsA;
    int t = threadIdx.x;
    int i = blk * 1024 + t;
    int v = (i < NN) ? in[i] : 0;
    sm[t] = v;
    __syncthreads();
    for (int off = 1; off < 1024; off <<= 1) {
        int add = (t >= off) ? sm[t - off] : 0;
        __syncthreads();
        sm[t] += add;
        __syncthreads();
    }
    if (i < NN) out[i] = sm[t] - v;            // exclusive
    if (t == 1023) bsum[blk] = sm[1023];
}

__global__ void scan_bsums(int* __restrict__ bsA, int* __restrict__ bsB)
{
    __shared__ int sm[128];
    int* bsum = blockIdx.x ? bsB : bsA;
    int t = threadIdx.x;
    int v = (t < 98) ? bsum[t] : 0;
    sm[t] = v;
    __syncthreads();
    for (int off = 1; off < 128; off <<= 1) {
        int add = (t >= off) ? sm[t - off] : 0;
        __syncthreads();
        sm[t] += add;
        __syncthreads();
    }
    if (t < 98) bsum[t] = sm[t] - v;           // exclusive
}

__global__ void scan_add(int* __restrict__ offs0, int* __restrict__ offs1,
                         const int* __restrict__ bsA, const int* __restrict__ bsB,
                         int* __restrict__ cur0, int* __restrict__ cur1,
                         u32* __restrict__ csr0, u32* __restrict__ csr1)
{
    int rel = blockIdx.x >= 392;
    int i = (blockIdx.x - rel * 392) * 256 + threadIdx.x;
    int* offs = rel ? offs1 : offs0;
    int* cur = rel ? cur1 : cur0;
    const int* bsum = rel ? bsB : bsA;
    if (i < NN) {
        int v = offs[i] + bsum[i >> 10];
        offs[i] = v;
        cur[i] = v;
    }
    if (i == 0) offs[NN] = NE;
    if (blockIdx.x == 0 && threadIdx.x < 8) {  // pads for gather batch over-read
        csr0[NE + threadIdx.x] = 0;
        csr1[NE + threadIdx.x] = 0;
    }
}

// ---------------- CSR build, XCD-partitioned, co-resident grid (2048 blocks) ----------------
// Entry = (src << 15) | (top 15 bits of f32(ew), round-to-nearest); decode = as_float(E<<17).
__global__ __launch_bounds__(256) void build_csr_part(
    const int* __restrict__ src0, const int* __restrict__ dst0,
    const float* __restrict__ ew0,
    const int* __restrict__ src1, const int* __restrict__ dst1,
    const float* __restrict__ ew1,
    int* __restrict__ cur0, int* __restrict__ cur1,
    u32* __restrict__ csr0, u32* __restrict__ csr1)
{
    int part = blockIdx.x & 7;
    int sub = blockIdx.x >> 3;
    int rel = sub & 1;
    int chunk = sub >> 1;
    const int lo = part * PART, hi = lo + PART;
    const int* src = rel ? src1 : src0;
    const int* dst = rel ? dst1 : dst0;
    const float* ew = rel ? ew1 : ew0;
    int* cur = rel ? cur1 : cur0;
    u32* csr = rel ? csr1 : csr0;
    const int e0 = chunk * ECH;
    const int e1 = min(e0 + ECH, NE);
    for (int e = e0 + threadIdx.x; e < e1; e += 256) {
        int d = dst[e];
        if (d >= lo && d < hi) {
            int p = atomicAdd(&cur[d], 1);
            u32 q = (__float_as_uint(ew[e]) + 0x10000u) >> 17;
            csr[p] = ((u32)src[e] << 15) | q;
        }
    }
}

// ---------------- software-pipelined gather (mean or max) ----------------
// Persistent: 8192 waves (2048 blocks x 4), wave = one relation, nodes w0, w0+S, ...
// 3-stage pipeline: iter i issues offs[i+3], csr batch [i+2], table rows [i+1],
// computes node i -> every load has a full iteration to land (hides the
// offs->csr->table serial chain that bounded the flat gather).
template<bool MAXAGG>
__global__ __launch_bounds__(256) void gather_pipe(
    const u16* __restrict__ F0, const u16* __restrict__ F1,
    const int* __restrict__ offs0, const u32* __restrict__ csr0, u16* __restrict__ o0,
    const int* __restrict__ offs1, const u32* __restrict__ csr1, u16* __restrict__ o1)
{
    int wid = blockIdx.x * 4 + (threadIdx.x >> 6);
    int rel = wid >= S;
    int w0 = wid - rel * S;
    const u16* F = rel ? F1 : F0;
    const int* offs = rel ? offs1 : offs0;
    const u32* csr = rel ? csr1 : csr0;
    u16* out = rel ? o1 : o0;
    const int lane2 = (threadIdx.x & 63) << 1;

#define LDOFFS(n, b, c) { int nc_ = min((n), NN - 1); b = offs[nc_]; \
                          c = ((n) < NN) ? (offs[nc_ + 1] - b) : 0; }
#define LDCSR(dst, b, c) { int last_ = max((c) - 1, 0); \
    _Pragma("unroll") for (int j = 0; j < 8; ++j) dst[j] = csr[(b) + min(j, last_)]; }
#define LDTBL(dst, E) { _Pragma("unroll") for (int j = 0; j < 8; ++j) \
    dst[j] = *reinterpret_cast<const u32*>(F + ((size_t)(E[j] >> 15) << 7) + lane2); }

    int bC, cC, bN, cN, bF, cF;
    u32 EC[8], EN[8], EF[8], vC[8], vN[8];
    LDOFFS(w0,         bC, cC);
    LDOFFS(w0 + S,     bN, cN);
    LDOFFS(w0 + 2 * S, bF, cF);
    LDCSR(EC, bC, cC);
    LDCSR(EN, bN, cN);
    LDTBL(vC, EC);

    for (int it = 0; it < NSTEP; ++it) {
        const int nC = w0 + it * S;
        int bF2, cF2;
        LDOFFS(nC + 3 * S, bF2, cF2);         // prefetch offs, node i+3
        LDCSR(EF, bF, cF);                    // prefetch csr,  node i+2
        LDTBL(vN, EN);                        // prefetch rows, node i+1

        float a0 = 0.f, a1 = 0.f;             // compute node i
#pragma unroll
        for (int j = 0; j < 8; ++j) {
            float wgt = (j < cC) ? __uint_as_float(EC[j] << 17) : 0.f;
            float f0 = __uint_as_float(vC[j] << 16);
            float f1 = __uint_as_float(vC[j] & 0xFFFF0000u);
            if (MAXAGG) { a0 = fmaxf(a0, f0 * wgt); a1 = fmaxf(a1, f1 * wgt); }
            else        { a0 = fmaf(f0, wgt, a0);   a1 = fmaf(f1, wgt, a1); }
        }
        for (int base = 8; base < cC; base += 8) {   // residual (deg > 8, ~15% of nodes)
#pragma unroll
            for (int j = 0; j < 8; ++j) {
                int idx = min(base + j, cC - 1);
                u32 E = csr[bC + idx];
                u32 v = *reinterpret_cast<const u32*>(F + ((size_t)(E >> 15) << 7) + lane2);
                float wgt = (base + j < cC) ? __uint_as_float(E << 17) : 0.f;
                float f0 = __uint_as_float(v << 16);
                float f1 = __uint_as_float(v & 0xFFFF0000u);
                if (MAXAGG) { a0 = fmaxf(a0, f0 * wgt); a1 = fmaxf(a1, f1 * wgt); }
                else        { a0 = fmaf(f0, wgt, a0);   a1 = fmaf(f1, wgt, a1); }
            }
        }
        if (nC < NN) {
            float s = MAXAGG ? 1.f : 1.f / fmaxf((float)cC, 1.f);
            ushort2 r; r.x = f2b(a0 * s); r.y = f2b(a1 * s);
            *reinterpret_cast<ushort2*>(out + (size_t)nC * 128 + lane2) = r;
        }
        bC = bN; cC = cN; bN = bF; cN = cF; bF = bF2; cF = cF2;   // rotate stages
#pragma unroll
        for (int j = 0; j < 8; ++j) { EC[j] = EN[j]; EN[j] = EF[j]; vC[j] = vN[j]; }
    }
#undef LDOFFS
#undef LDCSR
#undef LDTBL
}

// ---------------- register-B multi-pair MFMA GEMM (no LDS, no barriers) ----------------
// Per tile: issue ALL NPAIR*8 A-fragment loads into registers, then all MFMAs.
// __launch_bounds__(.,2) caps at 2 waves/EU -> 256 VGPR budget.
template<int NPAIR, int COLGROUPS, int WAVES, bool RELU, bool OUTF32, bool DUAL>
__global__ __launch_bounds__(WAVES * 64, 2) void gemm_reg(
    const u16* __restrict__ A0, const u16* __restrict__ A1, const u16* __restrict__ A2,
    const u16* __restrict__ BT, const float* __restrict__ bias,
    float* __restrict__ outF, u16* __restrict__ outB, u16* __restrict__ outB2)
{
    constexpr int NC = COLGROUPS * 32;
    constexpr int RT = WAVES / COLGROUPS;
    constexpr int OST = DUAL ? (NC / 2) : NC;
    constexpr int NTILES = NN / 32;
    const int w = threadIdx.x >> 6, l = threadIdx.x & 63;
    const int cg = w % COLGROUPS, rsub = w / COLGROUPS;
    const int l15 = l & 15, lk = (l >> 4) << 3, rq = (l >> 4) << 2;

    bf16x8 bfr[NPAIR][4][2];
#pragma unroll
    for (int p = 0; p < NPAIR; ++p)
#pragma unroll
        for (int ks = 0; ks < 4; ++ks)
#pragma unroll
            for (int cf = 0; cf < 2; ++cf) {
                int n = p * NC + cg * 32 + cf * 16 + l15;
                bfr[p][ks][cf] = *reinterpret_cast<const bf16x8*>(BT + (size_t)n * 128 + ks * 32 + lk);
            }

    const u16* As[3] = {A0, A1, A2};
    const float bv0 = bias[cg * 32 + l15];
    const float bv1 = bias[cg * 32 + 16 + l15];

    for (int tile = blockIdx.x * RT + rsub; tile < NTILES; tile += gridDim.x * RT) {
        const size_t rowbase = (size_t)tile * 32;

        bf16x8 af[NPAIR][4][2];
#pragma unroll
        for (int p = 0; p < NPAIR; ++p) {
            const u16* A = As[p] + rowbase * 128;
#pragma unroll
            for (int ks = 0; ks < 4; ++ks) {
                const int k0 = ks * 32 + lk;
                af[p][ks][0] = *reinterpret_cast<const bf16x8*>(A + (size_t)l15 * 128 + k0);
                af[p][ks][1] = *reinterpret_cast<const bf16x8*>(A + (size_t)(16 + l15) * 128 + k0);
            }
        }

        f32x4 acc[2][2];
#pragma unroll
        for (int rf = 0; rf < 2; ++rf)
#pragma unroll
            for (int cf = 0; cf < 2; ++cf)
                acc[rf][cf] = f32x4{0.f, 0.f, 0.f, 0.f};

#pragma unroll
        for (int p = 0; p < NPAIR; ++p)
#pragma unroll
            for (int ks = 0; ks < 4; ++ks) {
                acc[0][0] = __builtin_amdgcn_mfma_f32_16x16x32_bf16(af[p][ks][0], bfr[p][ks][0], acc[0][0], 0, 0, 0);
                acc[0][1] = __builtin_amdgcn_mfma_f32_16x16x32_bf16(af[p][ks][0], bfr[p][ks][1], acc[0][1], 0, 0, 0);
                acc[1][0] = __builtin_amdgcn_mfma_f32_16x16x32_bf16(af[p][ks][1], bfr[p][ks][0], acc[1][0], 0, 0, 0);
                acc[1][1] = __builtin_amdgcn_mfma_f32_16x16x32_bf16(af[p][ks][1], bfr[p][ks][1], acc[1][1], 0, 0, 0);
            }

        u16* ob = outB;
        if (DUAL && cg >= 4) ob = outB2;
        const int colbase = (DUAL ? (cg & 3) : cg) * 32;
#pragma unroll
        for (int cf = 0; cf < 2; ++cf) {
            const int col = colbase + cf * 16 + l15;
            const float bv = cf ? bv1 : bv0;
#pragma unroll
            for (int rf = 0; rf < 2; ++rf) {
#pragma unroll
                for (int j = 0; j < 4; ++j) {
                    const size_t row = rowbase + rf * 16 + rq + j;
                    float v = acc[rf][cf][j] + bv;
                    if (RELU) v = fmaxf(v, 0.f);
                    if (OUTF32) outF[row * OST + col] = v;
                    else        ob[row * OST + col] = f2b(v);
                }
            }
        }
    }
}

extern "C" void kernel_launch(void* const* d_in, const int* in_sizes, int n_in,
                              void* d_out, int out_size, void* d_ws, size_t ws_size,
                              hipStream_t stream)
{
    const float* x     = (const float*)d_in[0];
    const int*   src0  = (const int*)d_in[1];
    const int*   dst0  = (const int*)d_in[2];
    const float* ew0   = (const float*)d_in[3];
    const int*   src1  = (const int*)d_in[4];
    const int*   dst1  = (const int*)d_in[5];
    const float* ew1   = (const float*)d_in[6];
    const float* Ws0_0 = (const float*)d_in[7];
    const float* Wn0_0 = (const float*)d_in[8];
    const float* b0_0  = (const float*)d_in[9];
    const float* Wp_0  = (const float*)d_in[10];
    const float* bp_0  = (const float*)d_in[11];
    const float* Ws1_0 = (const float*)d_in[12];
    const float* Wn1_0 = (const float*)d_in[13];
    const float* b1_0  = (const float*)d_in[14];
    const float* Ws0_1 = (const float*)d_in[15];
    const float* Wn0_1 = (const float*)d_in[16];
    const float* b0_1  = (const float*)d_in[17];
    const float* Wp_1  = (const float*)d_in[18];
    const float* bp_1  = (const float*)d_in[19];
    const float* Ws1_1 = (const float*)d_in[20];
    const float* Wn1_1 = (const float*)d_in[21];
    const float* b1_1  = (const float*)d_in[22];

    char* ws = (char*)d_ws;
    u16*   x16   = (u16*)(ws + 0);            // x bf16; reused as hp0 later
    u16*   h16   = (u16*)(ws + 25600000);
    u16*   a0    = (u16*)(ws + 51200000);     // mean-agg r0; reused as max-agg r0
    u16*   a1    = (u16*)(ws + 76800000);     // mean-agg r1; reused as max-agg r1
    u16*   hp1   = (u16*)(ws + 102400000);
    u32*   csr0  = (u32*)(ws + 128000000);    // NE+8 packed entries
    u32*   csr1  = (u32*)(ws + 130400032);
    int*   offs0 = (int*)(ws + 132800064);
    int*   offs1 = (int*)(ws + 133200080);
    int*   cur0  = (int*)(ws + 133600096);
    int*   cur1  = (int*)(ws + 134000096);
    int*   deg0  = (int*)(ws + 134400096);
    int*   deg1  = (int*)(ws + 134800096);    // contiguous with deg0
    int*   bsA   = (int*)(ws + 135200096);
    int*   bsB   = (int*)(ws + 135200608);
    u16*   wts   = (u16*)(ws + 135201120);
    float* bsum0 = (float*)(ws + 135414112);
    float* bsum1 = (float*)(ws + 135414624);
    float* bpc   = (float*)(ws + 135415136);

    u16* hp0 = x16;                           // x16 dead after layer-0 GEMM

    hipMemsetAsync(deg0, 0, 800000, stream);
    fused_setup<<<14966, 256, 0, stream>>>(
        x, x16, Ws0_0, Ws0_1, Wn0_0, Wn0_1, Wp_0, Wp_1,
        Ws1_0, Ws1_1, Wn1_0, Wn1_1, b0_0, b0_1, b1_0, b1_1, bp_0, bp_1,
        wts, bsum0, bsum1, bpc, dst0, dst1, deg0, deg1);

    scan_local<<<196, 1024, 0, stream>>>(deg0, deg1, offs0, offs1, bsA, bsB);
    scan_bsums<<<2, 128, 0, stream>>>(bsA, bsB);
    scan_add<<<784, 256, 0, stream>>>(offs0, offs1, bsA, bsB, cur0, cur1, csr0, csr1);
    build_csr_part<<<2048, 256, 0, stream>>>(
        src0, dst0, ew0, src1, dst1, ew1, cur0, cur1, csr0, csr1);

    // ---- layer 0 ----
    gather_pipe<false><<<2048, 256, 0, stream>>>(
        x16, x16, offs0, csr0, a0, offs1, csr1, a1);
    gemm_reg<3, 4, 4, true, false, false><<<1024, 256, 0, stream>>>(
        x16, a0, a1, wts, bsum0, nullptr, h16, nullptr);

    // ---- layer 1 ----
    gemm_reg<1, 8, 8, true, false, true><<<512, 512, 0, stream>>>(
        h16, nullptr, nullptr, wts + 49152, bpc, nullptr, hp0, hp1);
    gather_pipe<true><<<2048, 256, 0, stream>>>(
        hp0, hp1, offs0, csr0, a0, offs1, csr1, a1);
    gemm_reg<3, 2, 4, false, true, false><<<782, 256, 0, stream>>>(
        h16, a0, a1, wts + 81920, bsum1, (float*)d_out, nullptr, nullptr);
}

// Round 14
// 372.355 us; speedup vs baseline: 1.1347x; 1.0891x over previous
//
#include <hip/hip_runtime.h>

typedef short bf16x8 __attribute__((ext_vector_type(8)));
typedef float f32x4 __attribute__((ext_vector_type(4)));
typedef unsigned short u16;
typedef unsigned int u32;

#define NN 100000
#define NE 600000
#define PART 12500        // NN / 8
#define ECH 4688          // ceil(NE / 128)

__device__ __forceinline__ u16 f2b(float f) {
    u32 u = __float_as_uint(f);
    return (u16)((u + 0x7FFFu + ((u >> 16) & 1u)) >> 16);
}

// ---------------- fused setup: XCD-part deg count | x->bf16 | weight prep ----------------
// Blocks 0..2047: degree count (co-resident-first -> blockIdx&7 == XCD holds).
// wts layout (u16): 0 Wsum0T[128][128], 16384 Wn0r0T, 32768 Wn0r1T,
//   49152 Wp0T[128][128], 65536 Wp1T, 81920 Wsum1T[64][128], 90112 Wn1r0T, 98304 Wn1r1T
__global__ void fused_setup(
    const float* __restrict__ x, u16* __restrict__ xo,
    const float* __restrict__ Ws0_0, const float* __restrict__ Ws0_1,
    const float* __restrict__ Wn0_0, const float* __restrict__ Wn0_1,
    const float* __restrict__ Wp_0,  const float* __restrict__ Wp_1,
    const float* __restrict__ Ws1_0, const float* __restrict__ Ws1_1,
    const float* __restrict__ Wn1_0, const float* __restrict__ Wn1_1,
    const float* __restrict__ b0_0, const float* __restrict__ b0_1,
    const float* __restrict__ b1_0, const float* __restrict__ b1_1,
    const float* __restrict__ bp_0, const float* __restrict__ bp_1,
    u16* __restrict__ w, float* __restrict__ bsum0, float* __restrict__ bsum1,
    float* __restrict__ bpc,
    const int* __restrict__ d0, const int* __restrict__ d1,
    int* __restrict__ g0, int* __restrict__ g1)
{
    int bb = blockIdx.x;
    if (bb < 2048) {                          // XCD-partitioned degree count
        int part = bb & 7;
        int sub = bb >> 3;
        int rel = sub & 1;
        int chunk = sub >> 1;
        const int lo = part * PART, hi = lo + PART;
        const int* d = rel ? d1 : d0;
        int* g = rel ? g1 : g0;
        const int e0 = chunk * ECH;
        const int e1 = min(e0 + ECH, NE);
        for (int e = e0 + threadIdx.x; e < e1; e += 256) {
            int dd = d[e];
            if (dd >= lo && dd < hi) atomicAdd(&g[dd], 1);
        }
    } else if (bb < 14548) {                  // x -> bf16 (12500 blocks)
        int t = (bb - 2048) * 256 + threadIdx.x;
        const float4 v = reinterpret_cast<const float4*>(x)[t];
        ushort4 r; r.x = f2b(v.x); r.y = f2b(v.y); r.z = f2b(v.z); r.w = f2b(v.w);
        reinterpret_cast<ushort4*>(xo)[t] = r;
    } else {                                  // weight prep (418 blocks)
        int t = (bb - 14548) * 256 + threadIdx.x;
        if (t < 81920) {                      // five 128x128 transposes
            int m = t >> 14, u = t & 16383;
            int n = u >> 7, k = u & 127;
            float v;
            if (m == 0)      v = Ws0_0[k * 128 + n] + Ws0_1[k * 128 + n];
            else if (m == 1) v = Wn0_0[k * 128 + n];
            else if (m == 2) v = Wn0_1[k * 128 + n];
            else if (m == 3) v = Wp_0[k * 128 + n];
            else             v = Wp_1[k * 128 + n];
            w[t] = f2b(v);
        } else if (t < 106496) {              // three 64x128 transposed
            int u = t - 81920;
            int m = u >> 13; u &= 8191;
            int n = u >> 7, k = u & 127;
            float v;
            if (m == 0)      v = Ws1_0[k * 64 + n] + Ws1_1[k * 64 + n];
            else if (m == 1) v = Wn1_0[k * 64 + n];
            else             v = Wn1_1[k * 64 + n];
            w[t] = f2b(v);
        } else if (t < 106624) {
            int i = t - 106496; bsum0[i] = b0_0[i] + b0_1[i];
        } else if (t < 106688) {
            int i = t - 106624; bsum1[i] = b1_0[i] + b1_1[i];
        } else if (t < 106944) {
            int i = t - 106688; bpc[i] = (i < 128) ? bp_0[i] : bp_1[i - 128];
        }
    }
}

// ---------------- prefix scan ----------------
__global__ void scan_local(const int* __restrict__ deg0, const int* __restrict__ deg1,
                           int* __restrict__ offs0, int* __restrict__ offs1,
                           int* __restrict__ bsA, int* __restrict__ bsB)
{
    __shared__ int sm[1024];
    int rel = blockIdx.x >= 98;
    int blk = blockIdx.x - rel * 98;
    const int* in = rel ? deg1 : deg0;
    int* out = rel ? offs1 : offs0;
    int* bsum = rel ? bsB : bsA;
    int t = threadIdx.x;
    int i = blk * 1024 + t;
    int v = (i < NN) ? in[i] : 0;
    sm[t] = v;
    __syncthreads();
    for (int off = 1; off < 1024; off <<= 1) {
        int add = (t >= off) ? sm[t - off] : 0;
        __syncthreads();
        sm[t] += add;
        __syncthreads();
    }
    if (i < NN) out[i] = sm[t] - v;            // exclusive
    if (t == 1023) bsum[blk] = sm[1023];
}

__global__ void scan_bsums(int* __restrict__ bsA, int* __restrict__ bsB)
{
    __shared__ int sm[128];
    int* bsum = blockIdx.x ? bsB : bsA;
    int t = threadIdx.x;
    int v = (t < 98) ? bsum[t] : 0;
    sm[t] = v;
    __syncthreads();
    for (int off = 1; off < 128; off <<= 1) {
        int add = (t >= off) ? sm[t - off] : 0;
        __syncthreads();
        sm[t] += add;
        __syncthreads();
    }
    if (t < 98) bsum[t] = sm[t] - v;           // exclusive
}

__global__ void scan_add(int* __restrict__ offs0, int* __restrict__ offs1,
                         const int* __restrict__ bsA, const int* __restrict__ bsB,
                         int* __restrict__ cur0, int* __restrict__ cur1,
                         u32* __restrict__ csr0, u32* __restrict__ csr1)
{
    int rel = blockIdx.x >= 392;
    int i = (blockIdx.x - rel * 392) * 256 + threadIdx.x;
    int* offs = rel ? offs1 : offs0;
    int* cur = rel ? cur1 : cur0;
    const int* bsum = rel ? bsB : bsA;
    if (i < NN) {
        int v = offs[i] + bsum[i >> 10];
        offs[i] = v;
        cur[i] = v;
    }
    if (i == 0) offs[NN] = NE;
    if (blockIdx.x == 0 && threadIdx.x < 8) {  // pads for gather batch over-read
        csr0[NE + threadIdx.x] = 0;
        csr1[NE + threadIdx.x] = 0;
    }
}

// ---------------- CSR build, XCD-partitioned, co-resident grid (2048 blocks) ----------------
// Entry = (src << 15) | (top 15 bits of f32(ew), round-to-nearest); decode = as_float(E<<17).
__global__ __launch_bounds__(256) void build_csr_part(
    const int* __restrict__ src0, const int* __restrict__ dst0,
    const float* __restrict__ ew0,
    const int* __restrict__ src1, const int* __restrict__ dst1,
    const float* __restrict__ ew1,
    int* __restrict__ cur0, int* __restrict__ cur1,
    u32* __restrict__ csr0, u32* __restrict__ csr1)
{
    int part = blockIdx.x & 7;
    int sub = blockIdx.x >> 3;
    int rel = sub & 1;
    int chunk = sub >> 1;
    const int lo = part * PART, hi = lo + PART;
    const int* src = rel ? src1 : src0;
    const int* dst = rel ? dst1 : dst0;
    const float* ew = rel ? ew1 : ew0;
    int* cur = rel ? cur1 : cur0;
    u32* csr = rel ? csr1 : csr0;
    const int e0 = chunk * ECH;
    const int e1 = min(e0 + ECH, NE);
    for (int e = e0 + threadIdx.x; e < e1; e += 256) {
        int d = dst[e];
        if (d >= lo && d < hi) {
            int p = atomicAdd(&cur[d], 1);
            u32 q = (__float_as_uint(ew[e]) + 0x10000u) >> 17;
            csr[p] = ((u32)src[e] << 15) | q;
        }
    }
}

// ---------------- flat gather (max), wave per node, unroll-8 ----------------
__global__ __launch_bounds__(256) void gather_max(
    const u16* __restrict__ F0, const u16* __restrict__ F1,
    const int* __restrict__ offs0, const u32* __restrict__ csr0, u16* __restrict__ o0,
    const int* __restrict__ offs1, const u32* __restrict__ csr1, u16* __restrict__ o1)
{
    int b = blockIdx.x;
    int rel = b >= 25000;
    const u16* F = rel ? F1 : F0;
    const int* offs = rel ? offs1 : offs0;
    const u32* csr = rel ? csr1 : csr0;
    u16* out = rel ? o1 : o0;
    int node = (b - rel * 25000) * 4 + (threadIdx.x >> 6);
    int lane2 = (threadIdx.x & 63) << 1;
    int beg = __builtin_amdgcn_readfirstlane(offs[node]);
    int end = __builtin_amdgcn_readfirstlane(offs[node + 1]);

    float a0 = 0.f, a1 = 0.f;
    for (int e = beg; e < end; e += 8) {
        u32 E[8], v[8];
#pragma unroll
        for (int i = 0; i < 8; ++i)
            E[i] = csr[e + i];
#pragma unroll
        for (int i = 0; i < 8; ++i)
            v[i] = *reinterpret_cast<const u32*>(F + ((size_t)(E[i] >> 15) << 7) + lane2);
#pragma unroll
        for (int i = 0; i < 8; ++i) {
            float wgt = (e + i < end) ? __uint_as_float(E[i] << 17) : 0.f;
            a0 = fmaxf(a0, __uint_as_float(v[i] << 16) * wgt);
            a1 = fmaxf(a1, __uint_as_float(v[i] & 0xFFFF0000u) * wgt);
        }
    }
    ushort2 r; r.x = f2b(a0); r.y = f2b(a1);
    *reinterpret_cast<ushort2*>(out + (size_t)node * 128 + lane2) = r;
}

// ---------------- fused mean-gather + layer-0 GEMM ----------------
// Block = 512 threads (8 waves), one 32-row tile. Phase 1: gather 32 nodes x 2 rels
// (wave wv: nodes 4wv..4wv+3, both rels concurrently for load-level parallelism)
// into XOR-swizzled LDS [64 rows][128 feats] bf16 (rows 0-31 rel0, 32-63 rel1).
// Phase 2: h = relu(x@Wsum0 + a0@Wn0r0 + a1@Wn0r1 + b); wave wv owns cols 16wv..16wv+15.
__global__ __launch_bounds__(512) void fused_l0(
    const u16* __restrict__ x16,
    const int* __restrict__ offs0, const u32* __restrict__ csr0,
    const int* __restrict__ offs1, const u32* __restrict__ csr1,
    const u16* __restrict__ BT, const float* __restrict__ bias,
    u16* __restrict__ outB)
{
    __shared__ char lds[64 * 256];
    const int tile = blockIdx.x;
    const int wv = threadIdx.x >> 6;
    const int l = threadIdx.x & 63;
    const int lane2 = l << 1;

    // ---- phase 1: gather ----
    for (int j = 0; j < 4; ++j) {
        const int nl = (wv << 2) + j;
        const int node = tile * 32 + nl;
        int begA = offs0[node], cntA = offs0[node + 1] - begA;
        int begB = offs1[node], cntB = offs1[node + 1] - begB;
        int lastA = max(cntA - 1, 0), lastB = max(cntB - 1, 0);
        float a0A = 0.f, a1A = 0.f, a0B = 0.f, a1B = 0.f;
        const int mx = max(cntA, cntB);
        for (int base = 0; base < mx; base += 8) {
            u32 EA[8], EB[8], vA[8], vB[8];
#pragma unroll
            for (int q = 0; q < 8; ++q) {
                EA[q] = csr0[begA + min(base + q, lastA)];
                EB[q] = csr1[begB + min(base + q, lastB)];
            }
#pragma unroll
            for (int q = 0; q < 8; ++q) {
                vA[q] = *reinterpret_cast<const u32*>(x16 + ((size_t)(EA[q] >> 15) << 7) + lane2);
                vB[q] = *reinterpret_cast<const u32*>(x16 + ((size_t)(EB[q] >> 15) << 7) + lane2);
            }
#pragma unroll
            for (int q = 0; q < 8; ++q) {
                float wA = (base + q < cntA) ? __uint_as_float(EA[q] << 17) : 0.f;
                float wB = (base + q < cntB) ? __uint_as_float(EB[q] << 17) : 0.f;
                a0A = fmaf(__uint_as_float(vA[q] << 16), wA, a0A);
                a1A = fmaf(__uint_as_float(vA[q] & 0xFFFF0000u), wA, a1A);
                a0B = fmaf(__uint_as_float(vB[q] << 16), wB, a0B);
                a1B = fmaf(__uint_as_float(vB[q] & 0xFFFF0000u), wB, a1B);
            }
        }
        float sA = 1.f / fmaxf((float)cntA, 1.f);
        float sB = 1.f / fmaxf((float)cntB, 1.f);
        const int rowA = nl, rowB = 32 + nl;
        *reinterpret_cast<u32*>(&lds[(rowA * 256 + l * 4) ^ ((rowA & 7) << 4)]) =
            (u32)f2b(a0A * sA) | ((u32)f2b(a1A * sA) << 16);
        *reinterpret_cast<u32*>(&lds[(rowB * 256 + l * 4) ^ ((rowB & 7) << 4)]) =
            (u32)f2b(a0B * sB) | ((u32)f2b(a1B * sB) << 16);
    }
    __syncthreads();

    // ---- phase 2: MFMA ----
    const int l15 = l & 15, lk = (l >> 4) << 3, rq = (l >> 4) << 2;
    bf16x8 bfr[3][4];
#pragma unroll
    for (int p = 0; p < 3; ++p)
#pragma unroll
        for (int ks = 0; ks < 4; ++ks) {
            int n = p * 128 + wv * 16 + l15;
            bfr[p][ks] = *reinterpret_cast<const bf16x8*>(BT + (size_t)n * 128 + ks * 32 + lk);
        }
    const size_t rowbase = (size_t)tile * 32;
    bf16x8 a0f[4], a1f[4];
#pragma unroll
    for (int ks = 0; ks < 4; ++ks) {
        int k0 = ks * 32 + lk;
        a0f[ks] = *reinterpret_cast<const bf16x8*>(x16 + (rowbase + l15) * 128 + k0);
        a1f[ks] = *reinterpret_cast<const bf16x8*>(x16 + (rowbase + 16 + l15) * 128 + k0);
    }
    f32x4 acc0 = f32x4{0.f, 0.f, 0.f, 0.f};
    f32x4 acc1 = f32x4{0.f, 0.f, 0.f, 0.f};
#pragma unroll
    for (int ks = 0; ks < 4; ++ks) {
        acc0 = __builtin_amdgcn_mfma_f32_16x16x32_bf16(a0f[ks], bfr[0][ks], acc0, 0, 0, 0);
        acc1 = __builtin_amdgcn_mfma_f32_16x16x32_bf16(a1f[ks], bfr[0][ks], acc1, 0, 0, 0);
    }
#pragma unroll
    for (int p = 1; p < 3; ++p) {
        const int rbase = (p - 1) * 32;
#pragma unroll
        for (int ks = 0; ks < 4; ++ks) {
            int k0 = ks * 32 + lk;
            int row0 = rbase + l15, row1 = rbase + 16 + l15;
            bf16x8 fa0 = *reinterpret_cast<const bf16x8*>(
                &lds[(row0 * 256 + k0 * 2) ^ ((row0 & 7) << 4)]);
            bf16x8 fa1 = *reinterpret_cast<const bf16x8*>(
                &lds[(row1 * 256 + k0 * 2) ^ ((row1 & 7) << 4)]);
            acc0 = __builtin_amdgcn_mfma_f32_16x16x32_bf16(fa0, bfr[p][ks], acc0, 0, 0, 0);
            acc1 = __builtin_amdgcn_mfma_f32_16x16x32_bf16(fa1, bfr[p][ks], acc1, 0, 0, 0);
        }
    }
    const int col = wv * 16 + l15;
    const float bv = bias[col];
#pragma unroll
    for (int j = 0; j < 4; ++j) {
        outB[(rowbase + rq + j) * 128 + col] = f2b(fmaxf(acc0[j] + bv, 0.f));
        outB[(rowbase + 16 + rq + j) * 128 + col] = f2b(fmaxf(acc1[j] + bv, 0.f));
    }
}

// ---------------- register-B multi-pair MFMA GEMM (no LDS, no barriers) ----------------
template<int NPAIR, int COLGROUPS, int WAVES, bool RELU, bool OUTF32, bool DUAL>
__global__ __launch_bounds__(WAVES * 64, 2) void gemm_reg(
    const u16* __restrict__ A0, const u16* __restrict__ A1, const u16* __restrict__ A2,
    const u16* __restrict__ BT, const float* __restrict__ bias,
    float* __restrict__ outF, u16* __restrict__ outB, u16* __restrict__ outB2)
{
    constexpr int NC = COLGROUPS * 32;
    constexpr int RT = WAVES / COLGROUPS;
    constexpr int OST = DUAL ? (NC / 2) : NC;
    constexpr int NTILES = NN / 32;
    const int w = threadIdx.x >> 6, l = threadIdx.x & 63;
    const int cg = w % COLGROUPS, rsub = w / COLGROUPS;
    const int l15 = l & 15, lk = (l >> 4) << 3, rq = (l >> 4) << 2;

    bf16x8 bfr[NPAIR][4][2];
#pragma unroll
    for (int p = 0; p < NPAIR; ++p)
#pragma unroll
        for (int ks = 0; ks < 4; ++ks)
#pragma unroll
            for (int cf = 0; cf < 2; ++cf) {
                int n = p * NC + cg * 32 + cf * 16 + l15;
                bfr[p][ks][cf] = *reinterpret_cast<const bf16x8*>(BT + (size_t)n * 128 + ks * 32 + lk);
            }

    const u16* As[3] = {A0, A1, A2};
    const float bv0 = bias[cg * 32 + l15];
    const float bv1 = bias[cg * 32 + 16 + l15];

    for (int tile = blockIdx.x * RT + rsub; tile < NTILES; tile += gridDim.x * RT) {
        const size_t rowbase = (size_t)tile * 32;

        bf16x8 af[NPAIR][4][2];
#pragma unroll
        for (int p = 0; p < NPAIR; ++p) {
            const u16* A = As[p] + rowbase * 128;
#pragma unroll
            for (int ks = 0; ks < 4; ++ks) {
                const int k0 = ks * 32 + lk;
                af[p][ks][0] = *reinterpret_cast<const bf16x8*>(A + (size_t)l15 * 128 + k0);
                af[p][ks][1] = *reinterpret_cast<const bf16x8*>(A + (size_t)(16 + l15) * 128 + k0);
            }
        }

        f32x4 acc[2][2];
#pragma unroll
        for (int rf = 0; rf < 2; ++rf)
#pragma unroll
            for (int cf = 0; cf < 2; ++cf)
                acc[rf][cf] = f32x4{0.f, 0.f, 0.f, 0.f};

#pragma unroll
        for (int p = 0; p < NPAIR; ++p)
#pragma unroll
            for (int ks = 0; ks < 4; ++ks) {
                acc[0][0] = __builtin_amdgcn_mfma_f32_16x16x32_bf16(af[p][ks][0], bfr[p][ks][0], acc[0][0], 0, 0, 0);
                acc[0][1] = __builtin_amdgcn_mfma_f32_16x16x32_bf16(af[p][ks][0], bfr[p][ks][1], acc[0][1], 0, 0, 0);
                acc[1][0] = __builtin_amdgcn_mfma_f32_16x16x32_bf16(af[p][ks][1], bfr[p][ks][0], acc[1][0], 0, 0, 0);
                acc[1][1] = __builtin_amdgcn_mfma_f32_16x16x32_bf16(af[p][ks][1], bfr[p][ks][1], acc[1][1], 0, 0, 0);
            }

        u16* ob = outB;
        if (DUAL && cg >= 4) ob = outB2;
        const int colbase = (DUAL ? (cg & 3) : cg) * 32;
#pragma unroll
        for (int cf = 0; cf < 2; ++cf) {
            const int col = colbase + cf * 16 + l15;
            const float bv = cf ? bv1 : bv0;
#pragma unroll
            for (int rf = 0; rf < 2; ++rf) {
#pragma unroll
                for (int j = 0; j < 4; ++j) {
                    const size_t row = rowbase + rf * 16 + rq + j;
                    float v = acc[rf][cf][j] + bv;
                    if (RELU) v = fmaxf(v, 0.f);
                    if (OUTF32) outF[row * OST + col] = v;
                    else        ob[row * OST + col] = f2b(v);
                }
            }
        }
    }
}

extern "C" void kernel_launch(void* const* d_in, const int* in_sizes, int n_in,
                              void* d_out, int out_size, void* d_ws, size_t ws_size,
                              hipStream_t stream)
{
    const float* x     = (const float*)d_in[0];
    const int*   src0  = (const int*)d_in[1];
    const int*   dst0  = (const int*)d_in[2];
    const float* ew0   = (const float*)d_in[3];
    const int*   src1  = (const int*)d_in[4];
    const int*   dst1  = (const int*)d_in[5];
    const float* ew1   = (const float*)d_in[6];
    const float* Ws0_0 = (const float*)d_in[7];
    const float* Wn0_0 = (const float*)d_in[8];
    const float* b0_0  = (const float*)d_in[9];
    const float* Wp_0  = (const float*)d_in[10];
    const float* bp_0  = (const float*)d_in[11];
    const float* Ws1_0 = (const float*)d_in[12];
    const float* Wn1_0 = (const float*)d_in[13];
    const float* b1_0  = (const float*)d_in[14];
    const float* Ws0_1 = (const float*)d_in[15];
    const float* Wn0_1 = (const float*)d_in[16];
    const float* b0_1  = (const float*)d_in[17];
    const float* Wp_1  = (const float*)d_in[18];
    const float* bp_1  = (const float*)d_in[19];
    const float* Ws1_1 = (const float*)d_in[20];
    const float* Wn1_1 = (const float*)d_in[21];
    const float* b1_1  = (const float*)d_in[22];

    char* ws = (char*)d_ws;
    u16*   x16   = (u16*)(ws + 0);            // x bf16; reused as hp0 later
    u16*   h16   = (u16*)(ws + 25600000);
    u16*   a0    = (u16*)(ws + 51200000);     // max-agg r0
    u16*   a1    = (u16*)(ws + 76800000);     // max-agg r1
    u16*   hp1   = (u16*)(ws + 102400000);
    u32*   csr0  = (u32*)(ws + 128000000);    // NE+8 packed entries
    u32*   csr1  = (u32*)(ws + 130400032);
    int*   offs0 = (int*)(ws + 132800064);
    int*   offs1 = (int*)(ws + 133200080);
    int*   cur0  = (int*)(ws + 133600096);
    int*   cur1  = (int*)(ws + 134000096);
    int*   deg0  = (int*)(ws + 134400096);
    int*   deg1  = (int*)(ws + 134800096);    // contiguous with deg0
    int*   bsA   = (int*)(ws + 135200096);
    int*   bsB   = (int*)(ws + 135200608);
    u16*   wts   = (u16*)(ws + 135201120);
    float* bsum0 = (float*)(ws + 135414112);
    float* bsum1 = (float*)(ws + 135414624);
    float* bpc   = (float*)(ws + 135415136);

    u16* hp0 = x16;                           // x16 dead after fused_l0

    hipMemsetAsync(deg0, 0, 800000, stream);
    fused_setup<<<14966, 256, 0, stream>>>(
        x, x16, Ws0_0, Ws0_1, Wn0_0, Wn0_1, Wp_0, Wp_1,
        Ws1_0, Ws1_1, Wn1_0, Wn1_1, b0_0, b0_1, b1_0, b1_1, bp_0, bp_1,
        wts, bsum0, bsum1, bpc, dst0, dst1, deg0, deg1);

    scan_local<<<196, 1024, 0, stream>>>(deg0, deg1, offs0, offs1, bsA, bsB);
    scan_bsums<<<2, 128, 0, stream>>>(bsA, bsB);
    scan_add<<<784, 256, 0, stream>>>(offs0, offs1, bsA, bsB, cur0, cur1, csr0, csr1);
    build_csr_part<<<2048, 256, 0, stream>>>(
        src0, dst0, ew0, src1, dst1, ew1, cur0, cur1, csr0, csr1);

    // ---- layer 0: fused mean-gather + GEMM ----
    fused_l0<<<3125, 512, 0, stream>>>(
        x16, offs0, csr0, offs1, csr1, wts, bsum0, h16);

    // ---- layer 1 ----
    gemm_reg<1, 8, 8, true, false, true><<<512, 512, 0, stream>>>(
        h16, nullptr, nullptr, wts + 49152, bpc, nullptr, hp0, hp1);
    gather_max<<<50000, 256, 0, stream>>>(
        hp0, hp1, offs0, csr0, a0, offs1, csr1, a1);
    gemm_reg<3, 2, 4, false, true, false><<<782, 256, 0, stream>>>(
        h16, a0, a1, wts + 81920, bsum1, (float*)d_out, nullptr, nullptr);
}

// Round 15
// 363.234 us; speedup vs baseline: 1.1632x; 1.0251x over previous
//
#include <hip/hip_runtime.h>

typedef short bf16x8 __attribute__((ext_vector_type(8)));
typedef float f32x4 __attribute__((ext_vector_type(4)));
typedef unsigned short u16;
typedef unsigned int u32;

#define NN 100000
#define NE 600000
#define PART 12500        // NN / 8
#define ECH 4688          // ceil(NE / 128)

__device__ __forceinline__ u16 f2b(float f) {
    u32 u = __float_as_uint(f);
    return (u16)((u + 0x7FFFu + ((u >> 16) & 1u)) >> 16);
}

// ---------------- fused setup: XCD-part deg count | x->bf16 | weight prep ----------------
// Blocks 0..2047: degree count (co-resident-first -> blockIdx&7 == XCD holds).
// wts layout (u16): 0 Wsum0T[128][128], 16384 Wn0r0T, 32768 Wn0r1T,
//   49152 Wp0T[128][128], 65536 Wp1T, 81920 Wsum1T[64][128], 90112 Wn1r0T, 98304 Wn1r1T
__global__ void fused_setup(
    const float* __restrict__ x, u16* __restrict__ xo,
    const float* __restrict__ Ws0_0, const float* __restrict__ Ws0_1,
    const float* __restrict__ Wn0_0, const float* __restrict__ Wn0_1,
    const float* __restrict__ Wp_0,  const float* __restrict__ Wp_1,
    const float* __restrict__ Ws1_0, const float* __restrict__ Ws1_1,
    const float* __restrict__ Wn1_0, const float* __restrict__ Wn1_1,
    const float* __restrict__ b0_0, const float* __restrict__ b0_1,
    const float* __restrict__ b1_0, const float* __restrict__ b1_1,
    const float* __restrict__ bp_0, const float* __restrict__ bp_1,
    u16* __restrict__ w, float* __restrict__ bsum0, float* __restrict__ bsum1,
    float* __restrict__ bpc,
    const int* __restrict__ d0, const int* __restrict__ d1,
    int* __restrict__ g0, int* __restrict__ g1)
{
    int bb = blockIdx.x;
    if (bb < 2048) {                          // XCD-partitioned degree count
        int part = bb & 7;
        int sub = bb >> 3;
        int rel = sub & 1;
        int chunk = sub >> 1;
        const int lo = part * PART, hi = lo + PART;
        const int* d = rel ? d1 : d0;
        int* g = rel ? g1 : g0;
        const int e0 = chunk * ECH;
        const int e1 = min(e0 + ECH, NE);
        for (int e = e0 + threadIdx.x; e < e1; e += 256) {
            int dd = d[e];
            if (dd >= lo && dd < hi) atomicAdd(&g[dd], 1);
        }
    } else if (bb < 14548) {                  // x -> bf16 (12500 blocks)
        int t = (bb - 2048) * 256 + threadIdx.x;
        const float4 v = reinterpret_cast<const float4*>(x)[t];
        ushort4 r; r.x = f2b(v.x); r.y = f2b(v.y); r.z = f2b(v.z); r.w = f2b(v.w);
        reinterpret_cast<ushort4*>(xo)[t] = r;
    } else {                                  // weight prep (418 blocks)
        int t = (bb - 14548) * 256 + threadIdx.x;
        if (t < 81920) {                      // five 128x128 transposes
            int m = t >> 14, u = t & 16383;
            int n = u >> 7, k = u & 127;
            float v;
            if (m == 0)      v = Ws0_0[k * 128 + n] + Ws0_1[k * 128 + n];
            else if (m == 1) v = Wn0_0[k * 128 + n];
            else if (m == 2) v = Wn0_1[k * 128 + n];
            else if (m == 3) v = Wp_0[k * 128 + n];
            else             v = Wp_1[k * 128 + n];
            w[t] = f2b(v);
        } else if (t < 106496) {              // three 64x128 transposed
            int u = t - 81920;
            int m = u >> 13; u &= 8191;
            int n = u >> 7, k = u & 127;
            float v;
            if (m == 0)      v = Ws1_0[k * 64 + n] + Ws1_1[k * 64 + n];
            else if (m == 1) v = Wn1_0[k * 64 + n];
            else             v = Wn1_1[k * 64 + n];
            w[t] = f2b(v);
        } else if (t < 106624) {
            int i = t - 106496; bsum0[i] = b0_0[i] + b0_1[i];
        } else if (t < 106688) {
            int i = t - 106624; bsum1[i] = b1_0[i] + b1_1[i];
        } else if (t < 106944) {
            int i = t - 106688; bpc[i] = (i < 128) ? bp_0[i] : bp_1[i - 128];
        }
    }
}

// ---------------- prefix scan ----------------
__global__ void scan_local(const int* __restrict__ deg0, const int* __restrict__ deg1,
                           int* __restrict__ offs0, int* __restrict__ offs1,
                           int* __restrict__ bsA, int* __restrict__ bsB)
{
    __shared__ int sm[1024];
    int rel = blockIdx.x >= 98;
    int blk = blockIdx.x - rel * 98;
    const int* in = rel ? deg1 : deg0;
    int* out = rel ? offs1 : offs0;
    int* bsum = rel ? bsB : bsA;
    int t = threadIdx.x;
    int i = blk * 1024 + t;
    int v = (i < NN) ? in[i] : 0;
    sm[t] = v;
    __syncthreads();
    for (int off = 1; off < 1024; off <<= 1) {
        int add = (t >= off) ? sm[t - off] : 0;
        __syncthreads();
        sm[t] += add;
        __syncthreads();
    }
    if (i < NN) out[i] = sm[t] - v;            // exclusive
    if (t == 1023) bsum[blk] = sm[1023];
}

__global__ void scan_bsums(int* __restrict__ bsA, int* __restrict__ bsB)
{
    __shared__ int sm[128];
    int* bsum = blockIdx.x ? bsB : bsA;
    int t = threadIdx.x;
    int v = (t < 98) ? bsum[t] : 0;
    sm[t] = v;
    __syncthreads();
    for (int off = 1; off < 128; off <<= 1) {
        int add = (t >= off) ? sm[t - off] : 0;
        __syncthreads();
        sm[t] += add;
        __syncthreads();
    }
    if (t < 98) bsum[t] = sm[t] - v;           // exclusive
}

__global__ void scan_add(int* __restrict__ offs0, int* __restrict__ offs1,
                         const int* __restrict__ bsA, const int* __restrict__ bsB,
                         int* __restrict__ cur0, int* __restrict__ cur1,
                         u32* __restrict__ csr0, u32* __restrict__ csr1)
{
    int rel = blockIdx.x >= 392;
    int i = (blockIdx.x - rel * 392) * 256 + threadIdx.x;
    int* offs = rel ? offs1 : offs0;
    int* cur = rel ? cur1 : cur0;
    const int* bsum = rel ? bsB : bsA;
    if (i < NN) {
        int v = offs[i] + bsum[i >> 10];
        offs[i] = v;
        cur[i] = v;
    }
    if (i == 0) offs[NN] = NE;
    if (blockIdx.x == 0 && threadIdx.x < 8) {  // pads for gather unroll-8 over-read
        csr0[NE + threadIdx.x] = 0;
        csr1[NE + threadIdx.x] = 0;
    }
}

// ---------------- CSR build, XCD-partitioned, co-resident grid (2048 blocks) ----------------
// Entry = (src << 15) | (top 15 bits of f32(ew), round-to-nearest); decode = as_float(E<<17).
__global__ __launch_bounds__(256) void build_csr_part(
    const int* __restrict__ src0, const int* __restrict__ dst0,
    const float* __restrict__ ew0,
    const int* __restrict__ src1, const int* __restrict__ dst1,
    const float* __restrict__ ew1,
    int* __restrict__ cur0, int* __restrict__ cur1,
    u32* __restrict__ csr0, u32* __restrict__ csr1)
{
    int part = blockIdx.x & 7;
    int sub = blockIdx.x >> 3;
    int rel = sub & 1;
    int chunk = sub >> 1;
    const int lo = part * PART, hi = lo + PART;
    const int* src = rel ? src1 : src0;
    const int* dst = rel ? dst1 : dst0;
    const float* ew = rel ? ew1 : ew0;
    int* cur = rel ? cur1 : cur0;
    u32* csr = rel ? csr1 : csr0;
    const int e0 = chunk * ECH;
    const int e1 = min(e0 + ECH, NE);
    for (int e = e0 + threadIdx.x; e < e1; e += 256) {
        int d = dst[e];
        if (d >= lo && d < hi) {
            int p = atomicAdd(&cur[d], 1);
            u32 q = (__float_as_uint(ew[e]) + 0x10000u) >> 17;
            csr[p] = ((u32)src[e] << 15) | q;
        }
    }
}

// ---------------- flat gather (mean or max), wave per node, unroll-8 ----------------
template<bool MAXAGG>
__global__ __launch_bounds__(256) void gather(
    const u16* __restrict__ F0, const u16* __restrict__ F1,
    const int* __restrict__ offs0, const u32* __restrict__ csr0, u16* __restrict__ o0,
    const int* __restrict__ offs1, const u32* __restrict__ csr1, u16* __restrict__ o1)
{
    int b = blockIdx.x;
    int rel = b >= 25000;
    const u16* F = rel ? F1 : F0;
    const int* offs = rel ? offs1 : offs0;
    const u32* csr = rel ? csr1 : csr0;
    u16* out = rel ? o1 : o0;
    int node = (b - rel * 25000) * 4 + (threadIdx.x >> 6);
    int lane2 = (threadIdx.x & 63) << 1;
    int beg = __builtin_amdgcn_readfirstlane(offs[node]);
    int end = __builtin_amdgcn_readfirstlane(offs[node + 1]);

    float a0 = 0.f, a1 = 0.f;
    for (int e = beg; e < end; e += 8) {
        u32 E[8], v[8];
#pragma unroll
        for (int i = 0; i < 8; ++i)
            E[i] = csr[e + i];
#pragma unroll
        for (int i = 0; i < 8; ++i)
            v[i] = *reinterpret_cast<const u32*>(F + ((size_t)(E[i] >> 15) << 7) + lane2);
#pragma unroll
        for (int i = 0; i < 8; ++i) {
            float wgt = (e + i < end) ? __uint_as_float(E[i] << 17) : 0.f;
            float f0 = __uint_as_float(v[i] << 16);
            float f1 = __uint_as_float(v[i] & 0xFFFF0000u);
            if (MAXAGG) { a0 = fmaxf(a0, f0 * wgt); a1 = fmaxf(a1, f1 * wgt); }
            else        { a0 = fmaf(f0, wgt, a0);   a1 = fmaf(f1, wgt, a1); }
        }
    }
    float s = MAXAGG ? 1.f : 1.f / fmaxf((float)(end - beg), 1.f);
    ushort2 r; r.x = f2b(a0 * s); r.y = f2b(a1 * s);
    *reinterpret_cast<ushort2*>(out + (size_t)node * 128 + lane2) = r;
}

// ---------------- register-B multi-pair MFMA GEMM (no LDS, no barriers) ----------------
// Per tile: issue ALL NPAIR*8 A-fragment loads into registers, then all MFMAs.
// __launch_bounds__(.,2) caps at 2 waves/EU -> 256 VGPR budget.
template<int NPAIR, int COLGROUPS, int WAVES, bool RELU, bool OUTF32, bool DUAL>
__global__ __launch_bounds__(WAVES * 64, 2) void gemm_reg(
    const u16* __restrict__ A0, const u16* __restrict__ A1, const u16* __restrict__ A2,
    const u16* __restrict__ BT, const float* __restrict__ bias,
    float* __restrict__ outF, u16* __restrict__ outB, u16* __restrict__ outB2)
{
    constexpr int NC = COLGROUPS * 32;
    constexpr int RT = WAVES / COLGROUPS;
    constexpr int OST = DUAL ? (NC / 2) : NC;
    constexpr int NTILES = NN / 32;
    const int w = threadIdx.x >> 6, l = threadIdx.x & 63;
    const int cg = w % COLGROUPS, rsub = w / COLGROUPS;
    const int l15 = l & 15, lk = (l >> 4) << 3, rq = (l >> 4) << 2;

    bf16x8 bfr[NPAIR][4][2];
#pragma unroll
    for (int p = 0; p < NPAIR; ++p)
#pragma unroll
        for (int ks = 0; ks < 4; ++ks)
#pragma unroll
            for (int cf = 0; cf < 2; ++cf) {
                int n = p * NC + cg * 32 + cf * 16 + l15;
                bfr[p][ks][cf] = *reinterpret_cast<const bf16x8*>(BT + (size_t)n * 128 + ks * 32 + lk);
            }

    const u16* As[3] = {A0, A1, A2};
    const float bv0 = bias[cg * 32 + l15];
    const float bv1 = bias[cg * 32 + 16 + l15];

    for (int tile = blockIdx.x * RT + rsub; tile < NTILES; tile += gridDim.x * RT) {
        const size_t rowbase = (size_t)tile * 32;

        bf16x8 af[NPAIR][4][2];
#pragma unroll
        for (int p = 0; p < NPAIR; ++p) {
            const u16* A = As[p] + rowbase * 128;
#pragma unroll
            for (int ks = 0; ks < 4; ++ks) {
                const int k0 = ks * 32 + lk;
                af[p][ks][0] = *reinterpret_cast<const bf16x8*>(A + (size_t)l15 * 128 + k0);
                af[p][ks][1] = *reinterpret_cast<const bf16x8*>(A + (size_t)(16 + l15) * 128 + k0);
            }
        }

        f32x4 acc[2][2];
#pragma unroll
        for (int rf = 0; rf < 2; ++rf)
#pragma unroll
            for (int cf = 0; cf < 2; ++cf)
                acc[rf][cf] = f32x4{0.f, 0.f, 0.f, 0.f};

#pragma unroll
        for (int p = 0; p < NPAIR; ++p)
#pragma unroll
            for (int ks = 0; ks < 4; ++ks) {
                acc[0][0] = __builtin_amdgcn_mfma_f32_16x16x32_bf16(af[p][ks][0], bfr[p][ks][0], acc[0][0], 0, 0, 0);
                acc[0][1] = __builtin_amdgcn_mfma_f32_16x16x32_bf16(af[p][ks][0], bfr[p][ks][1], acc[0][1], 0, 0, 0);
                acc[1][0] = __builtin_amdgcn_mfma_f32_16x16x32_bf16(af[p][ks][1], bfr[p][ks][0], acc[1][0], 0, 0, 0);
                acc[1][1] = __builtin_amdgcn_mfma_f32_16x16x32_bf16(af[p][ks][1], bfr[p][ks][1], acc[1][1], 0, 0, 0);
            }

        u16* ob = outB;
        if (DUAL && cg >= 4) ob = outB2;
        const int colbase = (DUAL ? (cg & 3) : cg) * 32;
#pragma unroll
        for (int cf = 0; cf < 2; ++cf) {
            const int col = colbase + cf * 16 + l15;
            const float bv = cf ? bv1 : bv0;
#pragma unroll
            for (int rf = 0; rf < 2; ++rf) {
#pragma unroll
                for (int j = 0; j < 4; ++j) {
                    const size_t row = rowbase + rf * 16 + rq + j;
                    float v = acc[rf][cf][j] + bv;
                    if (RELU) v = fmaxf(v, 0.f);
                    if (OUTF32) outF[row * OST + col] = v;
                    else        ob[row * OST + col] = f2b(v);
                }
            }
        }
    }
}

extern "C" void kernel_launch(void* const* d_in, const int* in_sizes, int n_in,
                              void* d_out, int out_size, void* d_ws, size_t ws_size,
                              hipStream_t stream)
{
    const float* x     = (const float*)d_in[0];
    const int*   src0  = (const int*)d_in[1];
    const int*   dst0  = (const int*)d_in[2];
    const float* ew0   = (const float*)d_in[3];
    const int*   src1  = (const int*)d_in[4];
    const int*   dst1  = (const int*)d_in[5];
    const float* ew1   = (const float*)d_in[6];
    const float* Ws0_0 = (const float*)d_in[7];
    const float* Wn0_0 = (const float*)d_in[8];
    const float* b0_0  = (const float*)d_in[9];
    const float* Wp_0  = (const float*)d_in[10];
    const float* bp_0  = (const float*)d_in[11];
    const float* Ws1_0 = (const float*)d_in[12];
    const float* Wn1_0 = (const float*)d_in[13];
    const float* b1_0  = (const float*)d_in[14];
    const float* Ws0_1 = (const float*)d_in[15];
    const float* Wn0_1 = (const float*)d_in[16];
    const float* b0_1  = (const float*)d_in[17];
    const float* Wp_1  = (const float*)d_in[18];
    const float* bp_1  = (const float*)d_in[19];
    const float* Ws1_1 = (const float*)d_in[20];
    const float* Wn1_1 = (const float*)d_in[21];
    const float* b1_1  = (const float*)d_in[22];

    char* ws = (char*)d_ws;
    u16*   x16   = (u16*)(ws + 0);            // x bf16; reused as hp0 later
    u16*   h16   = (u16*)(ws + 25600000);
    u16*   a0    = (u16*)(ws + 51200000);     // mean-agg r0; reused as max-agg r0
    u16*   a1    = (u16*)(ws + 76800000);     // mean-agg r1; reused as max-agg r1
    u16*   hp1   = (u16*)(ws + 102400000);
    u32*   csr0  = (u32*)(ws + 128000000);    // NE+8 packed entries
    u32*   csr1  = (u32*)(ws + 130400032);
    int*   offs0 = (int*)(ws + 132800064);
    int*   offs1 = (int*)(ws + 133200080);
    int*   cur0  = (int*)(ws + 133600096);
    int*   cur1  = (int*)(ws + 134000096);
    int*   deg0  = (int*)(ws + 134400096);
    int*   deg1  = (int*)(ws + 134800096);    // contiguous with deg0
    int*   bsA   = (int*)(ws + 135200096);
    int*   bsB   = (int*)(ws + 135200608);
    u16*   wts   = (u16*)(ws + 135201120);
    float* bsum0 = (float*)(ws + 135414112);
    float* bsum1 = (float*)(ws + 135414624);
    float* bpc   = (float*)(ws + 135415136);

    u16* hp0 = x16;                           // x16 dead after layer-0 GEMM

    hipMemsetAsync(deg0, 0, 800000, stream);
    fused_setup<<<14966, 256, 0, stream>>>(
        x, x16, Ws0_0, Ws0_1, Wn0_0, Wn0_1, Wp_0, Wp_1,
        Ws1_0, Ws1_1, Wn1_0, Wn1_1, b0_0, b0_1, b1_0, b1_1, bp_0, bp_1,
        wts, bsum0, bsum1, bpc, dst0, dst1, deg0, deg1);

    scan_local<<<196, 1024, 0, stream>>>(deg0, deg1, offs0, offs1, bsA, bsB);
    scan_bsums<<<2, 128, 0, stream>>>(bsA, bsB);
    scan_add<<<784, 256, 0, stream>>>(offs0, offs1, bsA, bsB, cur0, cur1, csr0, csr1);
    build_csr_part<<<2048, 256, 0, stream>>>(
        src0, dst0, ew0, src1, dst1, ew1, cur0, cur1, csr0, csr1);

    // ---- layer 0 ----
    gather<false><<<50000, 256, 0, stream>>>(
        x16, x16, offs0, csr0, a0, offs1, csr1, a1);
    gemm_reg<3, 4, 4, true, false, false><<<1024, 256, 0, stream>>>(
        x16, a0, a1, wts, bsum0, nullptr, h16, nullptr);

    // ---- layer 1 ----
    gemm_reg<1, 8, 8, true, false, true><<<512, 512, 0, stream>>>(
        h16, nullptr, nullptr, wts + 49152, bpc, nullptr, hp0, hp1);
    gather<true><<<50000, 256, 0, stream>>>(
        hp0, hp1, offs0, csr0, a0, offs1, csr1, a1);
    gemm_reg<3, 2, 4, false, true, false><<<782, 256, 0, stream>>>(
        h16, a0, a1, wts + 81920, bsum1, (float*)d_out, nullptr, nullptr);
}